// Round 13
// baseline (1768.578 us; speedup 1.0000x reference)
//
#include <hip/hip_runtime.h>

constexpr int NB  = 32;     // batch
constexpr int NMX = 256;    // NMAX
constexpr int ED  = 512;    // E
constexpr int HD  = 512;    // H
constexpr int UD  = 256;    // U
constexpr int MS  = 32;     // M steps
constexpr int PD  = 4;      // P
constexpr int SD  = 257;    // S = NMAX+1
constexpr int IL0 = 547;    // E + (M-1) + P
constexpr int XP  = 576;    // padded layer-0 input (18 f4 x 8 ks)

constexpr long long OFF_PTR  = 0;
constexpr long long OFF_COVL = (long long)NB*SD*MS;              // 263168
constexpr long long OFF_ENC  = OFF_COVL + 1;                     // 263169 (NOT 16B-aligned)
constexpr long long OFF_ADJ  = OFF_ENC + (long long)NB*SD*ED;    // 4473857
constexpr long long OFF_ATT  = OFF_ADJ + (long long)NB*(MS-1)*MS;// 4505601

__device__ __forceinline__ float sigf(float x){ return 1.0f/(1.0f + __expf(-x)); }
__device__ __forceinline__ float ftanh(float x){ float e = __expf(2.0f*x); return 1.0f - 2.0f/(e + 1.0f); }

// ==== merged prologue: encW1 GEMM + hid0 + enc-write + misc (round-12 proven) ====
__global__ __launch_bounds__(256) void k_pro(const float* __restrict__ hp,
    const float* __restrict__ hg, const float* __restrict__ embsp,
    const float* __restrict__ embpos, const float* __restrict__ W1,
    const float* __restrict__ Wih0, const float* __restrict__ W2,
    const int* __restrict__ nn, const float4* __restrict__ Wp4,
    const float* __restrict__ bp,
    float* __restrict__ out, float* __restrict__ encA, int useA,
    float4* __restrict__ encW1,
    float* __restrict__ x4, float* __restrict__ cov2, float* __restrict__ covp,
    float* __restrict__ Wih0_4, float* __restrict__ W2T,
    float* __restrict__ h0, float* __restrict__ h1){
  __shared__ __align__(16) float As[16][68];
  __shared__ __align__(16) float Bs[16][68];
  int blk = blockIdx.x, t = threadIdx.x;
  if (blk < 516){
    int bm = blk >> 2, bn = blk & 3;
    int m0 = bm*64, n0 = bn*64;
    int tm = t >> 4, tn = t & 15;
    float4 acc[4];
    #pragma unroll
    for (int i = 0; i < 4; ++i) acc[i] = {0.f,0.f,0.f,0.f};
    int arow = t >> 2, akq = t & 3;
    int r = m0 + arow;
    int amode = 0;
    const float* abase = embsp + ED;
    if (r < NB*SD){
      int ab = r / SD, as = r - ab*SD;
      if (as == 0) amode = 1;
      else if (as <= nn[ab]){ amode = 2; abase = hp + ((long long)ab*NMX + (as-1))*ED; }
    }
    int bk = t & 15, bu = t >> 4;
    for (int k0 = 0; k0 < 512; k0 += 16){
      float4 av = {0.f,0.f,0.f,0.f};
      if (amode) av = *(const float4*)(abase + k0 + akq*4);
      float bv[4];
      #pragma unroll
      for (int j = 0; j < 4; ++j)
        bv[j] = W1[(long long)(n0 + bu*4 + j)*ED + k0 + bk];
      __syncthreads();
      As[akq*4 + 0][arow] = av.x;
      As[akq*4 + 1][arow] = av.y;
      As[akq*4 + 2][arow] = av.z;
      As[akq*4 + 3][arow] = av.w;
      *(float4*)&Bs[bk][bu*4] = make_float4(bv[0], bv[1], bv[2], bv[3]);
      __syncthreads();
      #pragma unroll
      for (int kk = 0; kk < 16; ++kk){
        float4 a = *(const float4*)&As[kk][tm*4];
        float4 bq = *(const float4*)&Bs[kk][tn*4];
        acc[0].x += a.x*bq.x; acc[0].y += a.x*bq.y; acc[0].z += a.x*bq.z; acc[0].w += a.x*bq.w;
        acc[1].x += a.y*bq.x; acc[1].y += a.y*bq.y; acc[1].z += a.y*bq.z; acc[1].w += a.y*bq.w;
        acc[2].x += a.z*bq.x; acc[2].y += a.z*bq.y; acc[2].z += a.z*bq.z; acc[2].w += a.z*bq.w;
        acc[3].x += a.w*bq.x; acc[3].y += a.w*bq.y; acc[3].z += a.w*bq.z; acc[3].w += a.w*bq.w;
      }
    }
    #pragma unroll
    for (int i = 0; i < 4; ++i){
      int rr = m0 + tm*4 + i;
      if (rr < NB*SD) encW1[(long long)rr*64 + (n0 >> 2) + tn] = acc[i];
    }
  } else if (blk < 644){
    int b = t & 31;
    int row = (blk - 516)*8 + (t >> 5);            // 0..1023
    const float4* w = Wp4 + (long long)row*128;
    const float4* xg = (const float4*)(hg + (long long)b*ED);
    float acc = bp[row];
    #pragma unroll 4
    for (int i = 0; i < 128; ++i){
      float4 wv = w[i], xv = xg[i];
      acc += wv.x*xv.x + wv.y*xv.y + wv.z*xv.z + wv.w*xv.w;
    }
    float v = ftanh(acc);
    int h = row & 511;
    int idx = (h >> 2)*128 + b*4 + (h & 3);
    if (row < HD) h0[idx] = v;
    else          h1[idx] = v;
  } else {
    int eb = blk - 644;                             // 0..4111
    {
      int r = eb*2 + (t >> 7);
      int tid = t & 127;
      int b = r / SD, s = r - b*SD;
      float4 v = {0.f,0.f,0.f,0.f};
      if (s == 0) v = *(const float4*)(embsp + ED + tid*4);
      else if (s <= nn[b]) v = *(const float4*)(hp + ((long long)b*NMX + (s-1))*ED + tid*4);
      float* dst = out + OFF_ENC + (long long)r*ED + tid*4;
      dst[0] = v.x; dst[1] = v.y; dst[2] = v.z; dst[3] = v.w;
      if (useA) *(float4*)(encA + (long long)r*ED + tid*4) = v;
    }
    const int N0 = XP*NB;              // 18432 x4
    const int N1 = N0 + 2*NB*SD;       // +16448 cov double buffer
    const int N2 = N1 + 256;           // +256 covp
    const int N3 = N2 + 1536*XP;       // Wih0 repack
    const int N4 = N3 + ED*UD;         // W2T
    for (int i = eb*256 + t; i < N4; i += 4112*256){
      if (i < N0){
        int kb = i >> 7, rr = i & 3;
        int k = kb*4 + rr;
        float v;
        if (k < ED) v = embsp[k];
        else if (k < ED + MS - 1) v = 0.f;
        else if (k < IL0) v = embpos[k - (ED + MS - 1)];
        else v = 0.f;
        x4[i] = v;
      } else if (i < N1){
        cov2[i - N0] = 0.f;
      } else if (i < N2){
        covp[i - N1] = 0.f;
      } else if (i < N3){
        int j = i - N2; int row = j / XP, c = j % XP;
        Wih0_4[j] = (c < IL0) ? Wih0[(long long)row*IL0 + c] : 0.f;
      } else {
        int j = i - N3; int k = j / UD, u = j % UD;
        W2T[j] = W2[(long long)u*HD + k];
      }
    }
  }
}

// ==== hh-precompute: ghh[g][h][b] = h_prev @ Whh[g*H+h] (round-12 proven) ====
__device__ __forceinline__ void hh_pre(const float4* __restrict__ h4,
    const float4* __restrict__ Whh4, float* __restrict__ ghh,
    int bh, int t, float (*part)[NB][8][6]){
  int b = t & 31, ks = (t >> 5) & 7, hl = (t >> 8) & 1;
  int h = bh*2 + hl;
  float a0 = 0.f, a1 = 0.f, a2 = 0.f;
  const float4* w0 = Whh4 + (long long)(0*HD + h)*128 + ks*16;
  const float4* w1 = Whh4 + (long long)(1*HD + h)*128 + ks*16;
  const float4* w2 = Whh4 + (long long)(2*HD + h)*128 + ks*16;
  const float4* hb = h4 + (long long)(ks*16)*NB + b;
  #pragma unroll
  for (int kb = 0; kb < 16; ++kb){
    float4 xv = hb[kb*NB];
    float4 a = w0[kb], c = w1[kb], d = w2[kb];
    a0 += xv.x*a.x + xv.y*a.y + xv.z*a.z + xv.w*a.w;
    a1 += xv.x*c.x + xv.y*c.y + xv.z*c.z + xv.w*c.w;
    a2 += xv.x*d.x + xv.y*d.y + xv.z*d.z + xv.w*d.w;
  }
  part[hl][b][ks][0] = a0; part[hl][b][ks][1] = a1; part[hl][b][ks][2] = a2;
  __syncthreads();
  if (t < 64){
    int b2 = t & 31, hl2 = t >> 5;
    int h2 = bh*2 + hl2;
    float g0 = 0.f, g1 = 0.f, g2 = 0.f;
    #pragma unroll
    for (int k = 0; k < 8; ++k){
      g0 += part[hl2][b2][k][0]; g1 += part[hl2][b2][k][1]; g2 += part[hl2][b2][k][2];
    }
    ghh[(0*HD + h2)*NB + b2] = g0;
    ghh[(1*HD + h2)*NB + b2] = g1;
    ghh[(2*HD + h2)*NB + b2] = g2;
  }
}

// ==== GRU layer step; PRE -> hh gate sums read from ghh (round-12 proven) ====
template<int PER, bool PRE>
__global__ __launch_bounds__(512) void k_gru(const float4* __restrict__ x4,
                      const float4* __restrict__ h4,
                      const float4* __restrict__ Wih4, const float4* __restrict__ Whh4,
                      const float* __restrict__ bih, const float* __restrict__ bhh,
                      float* __restrict__ outT, const float* __restrict__ ghh){
  constexpr int NI4 = PER*8;
  __shared__ float part[2][NB][8][6];
  int t = threadIdx.x;
  int b = t & 31, ks = (t >> 5) & 7, hl = (t >> 8) & 1;
  int h = blockIdx.x*2 + hl;
  float ai0 = 0.f, ai1 = 0.f, ai2 = 0.f;
  {
    const float4* w0 = Wih4 + (long long)(0*HD + h)*NI4 + ks*PER;
    const float4* w1 = Wih4 + (long long)(1*HD + h)*NI4 + ks*PER;
    const float4* w2 = Wih4 + (long long)(2*HD + h)*NI4 + ks*PER;
    const float4* xb = x4 + (long long)(ks*PER)*NB + b;
    #pragma unroll
    for (int kb = 0; kb < PER; ++kb){
      float4 xv = xb[kb*NB];
      float4 a = w0[kb], c = w1[kb], d = w2[kb];
      ai0 += xv.x*a.x + xv.y*a.y + xv.z*a.z + xv.w*a.w;
      ai1 += xv.x*c.x + xv.y*c.y + xv.z*c.z + xv.w*c.w;
      ai2 += xv.x*d.x + xv.y*d.y + xv.z*d.z + xv.w*d.w;
    }
  }
  if (!PRE){
    float ah0 = 0.f, ah1 = 0.f, ah2 = 0.f;
    const float4* w0 = Whh4 + (long long)(0*HD + h)*128 + ks*16;
    const float4* w1 = Whh4 + (long long)(1*HD + h)*128 + ks*16;
    const float4* w2 = Whh4 + (long long)(2*HD + h)*128 + ks*16;
    const float4* hb = h4 + (long long)(ks*16)*NB + b;
    #pragma unroll
    for (int kb = 0; kb < 16; ++kb){
      float4 xv = hb[kb*NB];
      float4 a = w0[kb], c = w1[kb], d = w2[kb];
      ah0 += xv.x*a.x + xv.y*a.y + xv.z*a.z + xv.w*a.w;
      ah1 += xv.x*c.x + xv.y*c.y + xv.z*c.z + xv.w*c.w;
      ah2 += xv.x*d.x + xv.y*d.y + xv.z*d.z + xv.w*d.w;
    }
    part[hl][b][ks][3] = ah0; part[hl][b][ks][4] = ah1; part[hl][b][ks][5] = ah2;
  }
  part[hl][b][ks][0] = ai0; part[hl][b][ks][1] = ai1; part[hl][b][ks][2] = ai2;
  __syncthreads();
  if (t < 64){
    int b2 = t & 31, hl2 = t >> 5;
    int h2 = blockIdx.x*2 + hl2;
    float g0=0.f,g1=0.f,g2=0.f;
    #pragma unroll
    for (int k = 0; k < 8; ++k){
      g0 += part[hl2][b2][k][0]; g1 += part[hl2][b2][k][1]; g2 += part[hl2][b2][k][2];
    }
    float ghr, ghz, ghn;
    if (PRE){
      ghr = ghh[(0*HD + h2)*NB + b2];
      ghz = ghh[(1*HD + h2)*NB + b2];
      ghn = ghh[(2*HD + h2)*NB + b2];
    } else {
      float g3=0.f,g4=0.f,g5=0.f;
      #pragma unroll
      for (int k = 0; k < 8; ++k){
        g3 += part[hl2][b2][k][3]; g4 += part[hl2][b2][k][4]; g5 += part[hl2][b2][k][5];
      }
      ghr = g3; ghz = g4; ghn = g5;
    }
    float gir = g0 + bih[h2], giz = g1 + bih[HD + h2], gin = g2 + bih[2*HD + h2];
    ghr += bhh[h2]; ghz += bhh[HD + h2]; ghn += bhh[2*HD + h2];
    float r = sigf(gir + ghr);
    float z = sigf(giz + ghz);
    float nn = ftanh(gin + r*ghn);
    int idx = (h2 >> 2)*128 + b2*4 + (h2 & 3);
    float hp = ((const float*)h4)[idx];
    outT[idx] = (1.f - z)*nn + z*hp;
  }
}

// ==== fused attention (blocks 0..255) ∥ hh_pre1 (256..511) ∥ hh_pre0 (512..767) ====
// each unmasked (b,seg) block: q + ALL-257 scores + full softmax/argmax (bit-identical
// across the 8 blocks of b) then writes ONLY its own 33-row slice. cov double-buffered.
union __align__(16) AMem {
  struct { __align__(16) float h1s[512]; __align__(16) float wcs[256];
           __align__(16) float Vs[256];  __align__(16) float qs[256];
           __align__(16) float4 qpart[8][64]; float scs[SD];
           float red[8]; float redc[8]; int redi[8];
           float s_mx, s_den; int s_k; } a;
  float part[2][NB][8][6];
};

__global__ __launch_bounds__(512) void k_attn(const float4* __restrict__ h1,
                      const float4* __restrict__ W2T4, const float4* __restrict__ Wf4,
                      const float* __restrict__ bfv, const float* __restrict__ embpos,
                      int m, const float4* __restrict__ encW1,
                      const float4* __restrict__ wc4, const float4* __restrict__ V4,
                      const int* __restrict__ nn, const float* __restrict__ un,
                      const float* __restrict__ covc, float* __restrict__ covn,
                      float* __restrict__ covp, float* __restrict__ x4,
                      float* __restrict__ out, const float* __restrict__ encSrc,
                      int alignedA,
                      const float4* __restrict__ h0n4,
                      const float4* __restrict__ Whh0_4, float* __restrict__ ghh0,
                      const float4* __restrict__ Whh1_4, float* __restrict__ ghh1){
  __shared__ AMem sm;
  int t = threadIdx.x;
  if (blockIdx.x >= 512){ hh_pre(h0n4, Whh0_4, ghh0, blockIdx.x - 512, t, sm.part); return; }
  if (blockIdx.x >= 256){ hh_pre(h1,   Whh1_4, ghh1, blockIdx.x - 256, t, sm.part); return; }
  int b = blockIdx.x >> 3, seg = blockIdx.x & 7;
  int n = nn[b];
  int s0 = seg*33;
  if (seg != 0 && s0 > n){
    // fully masked slice: aj=0, ptr=0 (kk<=n<s0); cov rows stay 0 (never written)
    if (t < 33){
      int s = s0 + t;
      if (s < SD){
        out[OFF_ATT + ((long long)b*SD + s)*MS + m] = 0.f;
        out[OFF_PTR + ((long long)b*SD + s)*MS + m] = 0.f;
      }
    }
    return;
  }
  if (t < 128) ((float4*)sm.a.h1s)[t] = h1[t*NB + b];
  else if (t < 192) ((float4*)sm.a.wcs)[t - 128] = wc4[t - 128];
  else if (t < 256) ((float4*)sm.a.Vs)[t - 192] = V4[t - 192];
  __syncthreads();
  // q partials (redundant per block; identical FP order -> identical q)
  {
    int u4 = t & 63, kq = t >> 6;
    float4 acc = {0.f,0.f,0.f,0.f};
    const float4* w = W2T4 + (long long)(kq*64)*64 + u4;
    const float* hh = sm.a.h1s + kq*64;
    #pragma unroll 4
    for (int k = 0; k < 64; ++k){
      float a = hh[k];
      float4 wv = w[(long long)k*64];
      acc.x += a*wv.x; acc.y += a*wv.y; acc.z += a*wv.z; acc.w += a*wv.w;
    }
    sm.a.qpart[kq][u4] = acc;
  }
  __syncthreads();
  if (t < 64){
    float4 s = sm.a.qpart[0][t];
    #pragma unroll
    for (int k = 1; k < 8; ++k){
      float4 p = sm.a.qpart[k][t];
      s.x += p.x; s.y += p.y; s.z += p.z; s.w += p.w;
    }
    ((float4*)sm.a.qs)[t] = s;
  } else if (seg == 0){
    int w = (t >> 6) - 1;          // 0..6
    int lane = t & 63;
    for (int j = w; j < MS-1; j += 7){
      const float4* wf = Wf4 + (long long)j*128 + lane*2;
      float4 w0 = wf[0], w1v = wf[1];
      const float4* hh4 = (const float4*)sm.a.h1s + lane*2;
      float4 hv0 = hh4[0], hv1 = hh4[1];
      float d = w0.x*hv0.x + w0.y*hv0.y + w0.z*hv0.z + w0.w*hv0.w
              + w1v.x*hv1.x + w1v.y*hv1.y + w1v.z*hv1.z + w1v.w*hv1.w;
      for (int off = 32; off; off >>= 1) d += __shfl_xor(d, off);
      if (lane == 0){
        float th = (m < 1) ? 0.f : sigf(d + bfv[j]);
        out[OFF_ADJ + (long long)b*(MS-1)*MS + (long long)j*MS + m] = th;
        int k = ED + j;
        x4[(k >> 2)*128 + b*4 + (k & 3)] = th;
      }
    }
  }
  if (seg == 0 && t == 0 && m + 1 < MS){
    #pragma unroll
    for (int p = 0; p < PD; ++p){
      int k = ED + MS - 1 + p;
      x4[(k >> 2)*128 + b*4 + (k & 3)] = embpos[(m+1)*PD + p];
    }
  }
  __syncthreads();
  // scores for ALL rows (8x redundant across seg-blocks; L2-hot encW1)
  {
    int lane = t & 63, wav = t >> 6;
    float4 q4 = ((const float4*)sm.a.qs)[lane];
    float4 wv = ((const float4*)sm.a.wcs)[lane];
    float4 vv = ((const float4*)sm.a.Vs)[lane];
    for (int s = wav; s < SD; s += 8){
      if (s > n) continue;
      float cv2 = covc[b*SD + s];
      float4 e4 = encW1[((long long)b*SD + s)*64 + lane];
      float acc = vv.x*ftanh(e4.x + q4.x + cv2*wv.x)
                + vv.y*ftanh(e4.y + q4.y + cv2*wv.y)
                + vv.z*ftanh(e4.z + q4.z + cv2*wv.z)
                + vv.w*ftanh(e4.w + q4.w + cv2*wv.w);
      for (int off = 32; off; off >>= 1) acc += __shfl_xor(acc, off);
      if (lane == 0) sm.a.scs[s] = acc;
    }
  }
  __syncthreads();
  // full softmax + gumbel argmax (redundant, bit-identical); own-slice writes
  int lane = t & 63, wav = t >> 6;
  float sv = (t < SD && t <= n) ? sm.a.scs[t] : -3.4e38f;
  float cv = (t < SD) ? covc[b*SD + t] : 0.f;
  float v1 = sv;
  for (int off = 32; off; off >>= 1) v1 = fmaxf(v1, __shfl_xor(v1, off));
  if (lane == 0) sm.a.red[wav] = v1;
  __syncthreads();
  if (t == 0){
    float mm = sm.a.red[0];
    for (int i = 1; i < 8; ++i) mm = fmaxf(mm, sm.a.red[i]);
    sm.a.s_mx = mm;
  }
  __syncthreads();
  float ev = (t < SD && t <= n) ? __expf(sv - sm.a.s_mx) : 0.f;
  float v2 = ev;
  for (int off = 32; off; off >>= 1) v2 += __shfl_xor(v2, off);
  if (lane == 0) sm.a.red[wav] = v2;
  __syncthreads();
  if (t == 0){
    float ss = 0.f;
    for (int i = 0; i < 8; ++i) ss += sm.a.red[i];
    sm.a.s_den = ss;
  }
  __syncthreads();
  float aj = (t < SD) ? ev / sm.a.s_den : 0.f;
  float yl = -3.4e38f; int idx = SD;
  if (t < SD){
    float u = un[((long long)m*NB + b)*SD + t];
    float g = -__logf(-__logf(u + 1e-10f) + 1e-10f);
    yl = __logf(aj + 1e-12f) + g;
    idx = t;
  }
  // own-slice writes (atts/cov) + covl partial
  bool own = (t >= s0) && (t < s0 + 33) && (t < SD);
  float lcl = 0.f;
  if (own){
    out[OFF_ATT + ((long long)b*SD + t)*MS + m] = aj;
    covn[b*SD + t] = cv + aj;
    lcl = fminf(aj, cv);
  }
  for (int off = 32; off; off >>= 1){
    float oy = __shfl_xor(yl, off); int oi = __shfl_xor(idx, off);
    if (oy > yl || (oy == yl && oi < idx)){ yl = oy; idx = oi; }
  }
  for (int off = 32; off; off >>= 1) lcl += __shfl_xor(lcl, off);
  if (lane == 0){ sm.a.red[wav] = yl; sm.a.redi[wav] = idx; sm.a.redc[wav] = lcl; }
  __syncthreads();
  if (t == 0){
    float by = sm.a.red[0]; int bi = sm.a.redi[0]; float cl = sm.a.redc[0];
    for (int w = 1; w < 8; ++w){
      if (sm.a.red[w] > by || (sm.a.red[w] == by && sm.a.redi[w] < bi)){
        by = sm.a.red[w]; bi = sm.a.redi[w];
      }
      cl += sm.a.redc[w];
    }
    sm.a.s_k = bi;
    covp[b*8 + seg] += cl;
  }
  __syncthreads();
  int kk = sm.a.s_k;
  if (own) out[OFF_PTR + ((long long)b*SD + t)*MS + m] = (t == kk) ? 1.f : 0.f;
  if (seg == 0 && t < 128){
    if (alignedA){
      float4 v = ((const float4*)(encSrc + (long long)(b*SD + kk)*ED))[t];
      ((float4*)x4)[t*NB + b] = v;
    } else {
      const float* er = encSrc + (long long)(b*SD + kk)*ED;  // unaligned base
      float4 v; v.x = er[t*4]; v.y = er[t*4+1]; v.z = er[t*4+2]; v.w = er[t*4+3];
      ((float4*)x4)[t*NB + b] = v;
    }
  }
}

__global__ void k_fin(const float* __restrict__ covp, float* __restrict__ out){
  __shared__ float r4[4];
  int t = threadIdx.x;
  float v = covp[t];
  for (int off = 32; off; off >>= 1) v += __shfl_xor(v, off);
  if ((t & 63) == 0) r4[t >> 6] = v;
  __syncthreads();
  if (t == 0) out[OFF_COVL] = (r4[0] + r4[1] + r4[2] + r4[3]) / (float)NB;
}

extern "C" void kernel_launch(void* const* d_in, const int* in_sizes, int n_in,
                              void* d_out, int out_size, void* d_ws, size_t ws_size,
                              hipStream_t stream){
  const float* h_padded    = (const float*)d_in[0];
  const float* hg          = (const float*)d_in[1];
  const int*   num_nodes   = (const int*)  d_in[2];
  const float* u_noise     = (const float*)d_in[3];
  const float* emb_special = (const float*)d_in[4];
  const float* emb_pos     = (const float*)d_in[5];
  const float* Wp          = (const float*)d_in[6];
  const float* bp          = (const float*)d_in[7];
  const float* W_ih0       = (const float*)d_in[8];
  const float* W_hh0       = (const float*)d_in[9];
  const float* b_ih0       = (const float*)d_in[10];
  const float* b_hh0       = (const float*)d_in[11];
  const float* W_ih1       = (const float*)d_in[12];
  const float* W_hh1       = (const float*)d_in[13];
  const float* b_ih1       = (const float*)d_in[14];
  const float* b_hh1       = (const float*)d_in[15];
  const float* W1          = (const float*)d_in[16];
  const float* W2          = (const float*)d_in[17];
  const float* wc          = (const float*)d_in[18];
  const float* V           = (const float*)d_in[19];
  const float* Wf          = (const float*)d_in[20];
  const float* bf          = (const float*)d_in[21];
  float* out = (float*)d_out;

  float* ws      = (float*)d_ws;
  float* encW1   = ws;  ws += (long long)NB*SD*UD;   // 2,105,344
  float* Wih0_4  = ws;  ws += (long long)1536*XP;    // 884,736
  float* W2T     = ws;  ws += (long long)UD*ED;      // 131,072
  float* x4      = ws;  ws += XP*NB;                 // 18,432
  float* h0      = ws;  ws += 2*HD*NB;               // 32,768
  float* h1      = ws;  ws += 2*HD*NB;               // 32,768
  float* cov2    = ws;  ws += 2*NB*SD;               // 16,448 (double buffer)
  float* covp    = ws;  ws += 256;                   // 256
  float* ghh0    = ws;  ws += 3*HD*NB;               // 49,152
  float* ghh1    = ws;  ws += 3*HD*NB;               // 49,152
  float* encA    = ws;  // optional aligned enc copy: +4,210,688 floats
  size_t used_base = (size_t)((char*)ws - (char*)d_ws);
  int useA = (ws_size >= used_base + (size_t)NB*SD*ED*sizeof(float)) ? 1 : 0;
  const float* encSrc = useA ? encA : (out + OFF_ENC);

  k_pro<<<4756, 256, 0, stream>>>(h_padded, hg, emb_special, emb_pos, W1, W_ih0, W2,
                                  num_nodes, (const float4*)Wp, bp, out, encA, useA,
                                  (float4*)encW1, x4, cov2, covp, Wih0_4, W2T, h0, h1);

  for (int m = 0; m < MS; ++m){
    float* h0c = h0 + (m & 1)*HD*NB;
    float* h0n = h0 + ((m + 1) & 1)*HD*NB;
    float* h1c = h1 + (m & 1)*HD*NB;
    float* h1n = h1 + ((m + 1) & 1)*HD*NB;
    float* covc = cov2 + (m & 1)*NB*SD;
    float* covn = cov2 + ((m + 1) & 1)*NB*SD;
    if (m == 0){
      k_gru<18,false><<<256, 512, 0, stream>>>((const float4*)x4, (const float4*)h0c,
          (const float4*)Wih0_4, (const float4*)W_hh0, b_ih0, b_hh0, h0n, nullptr);
      k_gru<16,false><<<256, 512, 0, stream>>>((const float4*)h0n, (const float4*)h1c,
          (const float4*)W_ih1, (const float4*)W_hh1, b_ih1, b_hh1, h1n, nullptr);
    } else {
      k_gru<18,true><<<256, 512, 0, stream>>>((const float4*)x4, (const float4*)h0c,
          (const float4*)Wih0_4, (const float4*)W_hh0, b_ih0, b_hh0, h0n, ghh0);
      k_gru<16,true><<<256, 512, 0, stream>>>((const float4*)h0n, (const float4*)h1c,
          (const float4*)W_ih1, (const float4*)W_hh1, b_ih1, b_hh1, h1n, ghh1);
    }
    k_attn<<<768, 512, 0, stream>>>((const float4*)h1n, (const float4*)W2T,
        (const float4*)Wf, bf, emb_pos, m, (const float4*)encW1,
        (const float4*)wc, (const float4*)V, num_nodes, u_noise,
        covc, covn, covp, x4, out, encSrc, useA,
        (const float4*)h0n, (const float4*)W_hh0, ghh0,
        (const float4*)W_hh1, ghh1);
  }
  k_fin<<<1, 256, 0, stream>>>(covp, out);
}

// Round 14
// 1364.127 us; speedup vs baseline: 1.2965x; 1.2965x over previous
//
#include <hip/hip_runtime.h>

constexpr int NB  = 32;     // batch
constexpr int NMX = 256;    // NMAX
constexpr int ED  = 512;    // E
constexpr int HD  = 512;    // H
constexpr int UD  = 256;    // U
constexpr int MS  = 32;     // M steps
constexpr int PD  = 4;      // P
constexpr int SD  = 257;    // S = NMAX+1
constexpr int IL0 = 547;    // E + (M-1) + P
constexpr int XP  = 576;    // padded layer-0 input (18 f4 x 8 ks)

constexpr long long OFF_PTR  = 0;
constexpr long long OFF_COVL = (long long)NB*SD*MS;              // 263168
constexpr long long OFF_ENC  = OFF_COVL + 1;                     // 263169 (NOT 16B-aligned)
constexpr long long OFF_ADJ  = OFF_ENC + (long long)NB*SD*ED;    // 4473857
constexpr long long OFF_ATT  = OFF_ADJ + (long long)NB*(MS-1)*MS;// 4505601

__device__ __forceinline__ float sigf(float x){ return 1.0f/(1.0f + __expf(-x)); }
__device__ __forceinline__ float ftanh(float x){ float e = __expf(2.0f*x); return 1.0f - 2.0f/(e + 1.0f); }

// ==== merged prologue: encW1 GEMM + hid0 + enc-write + misc (round-12 proven) ====
__global__ __launch_bounds__(256) void k_pro(const float* __restrict__ hp,
    const float* __restrict__ hg, const float* __restrict__ embsp,
    const float* __restrict__ embpos, const float* __restrict__ W1,
    const float* __restrict__ Wih0, const float* __restrict__ W2,
    const int* __restrict__ nn, const float4* __restrict__ Wp4,
    const float* __restrict__ bp,
    float* __restrict__ out, float* __restrict__ encA, int useA,
    float4* __restrict__ encW1,
    float* __restrict__ x4, float* __restrict__ cov, float* __restrict__ covl,
    float* __restrict__ Wih0_4, float* __restrict__ W2T,
    float* __restrict__ h0, float* __restrict__ h1, int* __restrict__ tick){
  __shared__ __align__(16) float As[16][68];
  __shared__ __align__(16) float Bs[16][68];
  int blk = blockIdx.x, t = threadIdx.x;
  if (blk < 516){
    int bm = blk >> 2, bn = blk & 3;
    int m0 = bm*64, n0 = bn*64;
    int tm = t >> 4, tn = t & 15;
    float4 acc[4];
    #pragma unroll
    for (int i = 0; i < 4; ++i) acc[i] = {0.f,0.f,0.f,0.f};
    int arow = t >> 2, akq = t & 3;
    int r = m0 + arow;
    int amode = 0;
    const float* abase = embsp + ED;
    if (r < NB*SD){
      int ab = r / SD, as = r - ab*SD;
      if (as == 0) amode = 1;
      else if (as <= nn[ab]){ amode = 2; abase = hp + ((long long)ab*NMX + (as-1))*ED; }
    }
    int bk = t & 15, bu = t >> 4;
    for (int k0 = 0; k0 < 512; k0 += 16){
      float4 av = {0.f,0.f,0.f,0.f};
      if (amode) av = *(const float4*)(abase + k0 + akq*4);
      float bv[4];
      #pragma unroll
      for (int j = 0; j < 4; ++j)
        bv[j] = W1[(long long)(n0 + bu*4 + j)*ED + k0 + bk];
      __syncthreads();
      As[akq*4 + 0][arow] = av.x;
      As[akq*4 + 1][arow] = av.y;
      As[akq*4 + 2][arow] = av.z;
      As[akq*4 + 3][arow] = av.w;
      *(float4*)&Bs[bk][bu*4] = make_float4(bv[0], bv[1], bv[2], bv[3]);
      __syncthreads();
      #pragma unroll
      for (int kk = 0; kk < 16; ++kk){
        float4 a = *(const float4*)&As[kk][tm*4];
        float4 bq = *(const float4*)&Bs[kk][tn*4];
        acc[0].x += a.x*bq.x; acc[0].y += a.x*bq.y; acc[0].z += a.x*bq.z; acc[0].w += a.x*bq.w;
        acc[1].x += a.y*bq.x; acc[1].y += a.y*bq.y; acc[1].z += a.y*bq.z; acc[1].w += a.y*bq.w;
        acc[2].x += a.z*bq.x; acc[2].y += a.z*bq.y; acc[2].z += a.z*bq.z; acc[2].w += a.z*bq.w;
        acc[3].x += a.w*bq.x; acc[3].y += a.w*bq.y; acc[3].z += a.w*bq.z; acc[3].w += a.w*bq.w;
      }
    }
    #pragma unroll
    for (int i = 0; i < 4; ++i){
      int rr = m0 + tm*4 + i;
      if (rr < NB*SD) encW1[(long long)rr*64 + (n0 >> 2) + tn] = acc[i];
    }
  } else if (blk < 644){
    int b = t & 31;
    int row = (blk - 516)*8 + (t >> 5);            // 0..1023
    const float4* w = Wp4 + (long long)row*128;
    const float4* xg = (const float4*)(hg + (long long)b*ED);
    float acc = bp[row];
    #pragma unroll 4
    for (int i = 0; i < 128; ++i){
      float4 wv = w[i], xv = xg[i];
      acc += wv.x*xv.x + wv.y*xv.y + wv.z*xv.z + wv.w*xv.w;
    }
    float v = ftanh(acc);
    int h = row & 511;
    int idx = (h >> 2)*128 + b*4 + (h & 3);
    if (row < HD) h0[idx] = v;
    else          h1[idx] = v;
  } else {
    int eb = blk - 644;                             // 0..4111
    {
      int r = eb*2 + (t >> 7);
      int tid = t & 127;
      int b = r / SD, s = r - b*SD;
      float4 v = {0.f,0.f,0.f,0.f};
      if (s == 0) v = *(const float4*)(embsp + ED + tid*4);
      else if (s <= nn[b]) v = *(const float4*)(hp + ((long long)b*NMX + (s-1))*ED + tid*4);
      float* dst = out + OFF_ENC + (long long)r*ED + tid*4;
      dst[0] = v.x; dst[1] = v.y; dst[2] = v.z; dst[3] = v.w;
      if (useA) *(float4*)(encA + (long long)r*ED + tid*4) = v;
    }
    const int N0 = XP*NB;              // 18432 x4
    const int N1 = N0 + NB*SD;         // +8224 cov
    const int N2 = N1 + NB;            // +32 covl
    const int N3 = N2 + 1536*XP;       // Wih0 repack
    const int N4 = N3 + ED*UD;         // W2T
    const int N5 = N4 + MS*NB;         // tick (zeroed EVERY call: replay-safe)
    for (int i = eb*256 + t; i < N5; i += 4112*256){
      if (i < N0){
        int kb = i >> 7, rr = i & 3;
        int k = kb*4 + rr;
        float v;
        if (k < ED) v = embsp[k];
        else if (k < ED + MS - 1) v = 0.f;
        else if (k < IL0) v = embpos[k - (ED + MS - 1)];
        else v = 0.f;
        x4[i] = v;
      } else if (i < N1){
        cov[i - N0] = 0.f;
      } else if (i < N2){
        covl[i - N1] = 0.f;
      } else if (i < N3){
        int j = i - N2; int row = j / XP, c = j % XP;
        Wih0_4[j] = (c < IL0) ? Wih0[(long long)row*IL0 + c] : 0.f;
      } else if (i < N4){
        int j = i - N3; int k = j / UD, u = j % UD;
        W2T[j] = W2[(long long)u*HD + k];
      } else {
        tick[i - N4] = 0;
      }
    }
  }
}

// ==== hh-precompute: ghh[g][h][b] = h_prev @ Whh[g*H+h] (round-12 proven) ====
__device__ __forceinline__ void hh_pre(const float4* __restrict__ h4,
    const float4* __restrict__ Whh4, float* __restrict__ ghh,
    int bh, int t, float (*part)[NB][8][6]){
  int b = t & 31, ks = (t >> 5) & 7, hl = (t >> 8) & 1;
  int h = bh*2 + hl;
  float a0 = 0.f, a1 = 0.f, a2 = 0.f;
  const float4* w0 = Whh4 + (long long)(0*HD + h)*128 + ks*16;
  const float4* w1 = Whh4 + (long long)(1*HD + h)*128 + ks*16;
  const float4* w2 = Whh4 + (long long)(2*HD + h)*128 + ks*16;
  const float4* hb = h4 + (long long)(ks*16)*NB + b;
  #pragma unroll
  for (int kb = 0; kb < 16; ++kb){
    float4 xv = hb[kb*NB];
    float4 a = w0[kb], c = w1[kb], d = w2[kb];
    a0 += xv.x*a.x + xv.y*a.y + xv.z*a.z + xv.w*a.w;
    a1 += xv.x*c.x + xv.y*c.y + xv.z*c.z + xv.w*c.w;
    a2 += xv.x*d.x + xv.y*d.y + xv.z*d.z + xv.w*d.w;
  }
  part[hl][b][ks][0] = a0; part[hl][b][ks][1] = a1; part[hl][b][ks][2] = a2;
  __syncthreads();
  if (t < 64){
    int b2 = t & 31, hl2 = t >> 5;
    int h2 = bh*2 + hl2;
    float g0 = 0.f, g1 = 0.f, g2 = 0.f;
    #pragma unroll
    for (int k = 0; k < 8; ++k){
      g0 += part[hl2][b2][k][0]; g1 += part[hl2][b2][k][1]; g2 += part[hl2][b2][k][2];
    }
    ghh[(0*HD + h2)*NB + b2] = g0;
    ghh[(1*HD + h2)*NB + b2] = g1;
    ghh[(2*HD + h2)*NB + b2] = g2;
  }
}

// ==== GRU layer step; PRE -> hh gate sums read from ghh (round-12 proven) ====
template<int PER, bool PRE>
__global__ __launch_bounds__(512) void k_gru(const float4* __restrict__ x4,
                      const float4* __restrict__ h4,
                      const float4* __restrict__ Wih4, const float4* __restrict__ Whh4,
                      const float* __restrict__ bih, const float* __restrict__ bhh,
                      float* __restrict__ outT, const float* __restrict__ ghh){
  constexpr int NI4 = PER*8;
  __shared__ float part[2][NB][8][6];
  int t = threadIdx.x;
  int b = t & 31, ks = (t >> 5) & 7, hl = (t >> 8) & 1;
  int h = blockIdx.x*2 + hl;
  float ai0 = 0.f, ai1 = 0.f, ai2 = 0.f;
  {
    const float4* w0 = Wih4 + (long long)(0*HD + h)*NI4 + ks*PER;
    const float4* w1 = Wih4 + (long long)(1*HD + h)*NI4 + ks*PER;
    const float4* w2 = Wih4 + (long long)(2*HD + h)*NI4 + ks*PER;
    const float4* xb = x4 + (long long)(ks*PER)*NB + b;
    #pragma unroll
    for (int kb = 0; kb < PER; ++kb){
      float4 xv = xb[kb*NB];
      float4 a = w0[kb], c = w1[kb], d = w2[kb];
      ai0 += xv.x*a.x + xv.y*a.y + xv.z*a.z + xv.w*a.w;
      ai1 += xv.x*c.x + xv.y*c.y + xv.z*c.z + xv.w*c.w;
      ai2 += xv.x*d.x + xv.y*d.y + xv.z*d.z + xv.w*d.w;
    }
  }
  if (!PRE){
    float ah0 = 0.f, ah1 = 0.f, ah2 = 0.f;
    const float4* w0 = Whh4 + (long long)(0*HD + h)*128 + ks*16;
    const float4* w1 = Whh4 + (long long)(1*HD + h)*128 + ks*16;
    const float4* w2 = Whh4 + (long long)(2*HD + h)*128 + ks*16;
    const float4* hb = h4 + (long long)(ks*16)*NB + b;
    #pragma unroll
    for (int kb = 0; kb < 16; ++kb){
      float4 xv = hb[kb*NB];
      float4 a = w0[kb], c = w1[kb], d = w2[kb];
      ah0 += xv.x*a.x + xv.y*a.y + xv.z*a.z + xv.w*a.w;
      ah1 += xv.x*c.x + xv.y*c.y + xv.z*c.z + xv.w*c.w;
      ah2 += xv.x*d.x + xv.y*d.y + xv.z*d.z + xv.w*d.w;
    }
    part[hl][b][ks][3] = ah0; part[hl][b][ks][4] = ah1; part[hl][b][ks][5] = ah2;
  }
  part[hl][b][ks][0] = ai0; part[hl][b][ks][1] = ai1; part[hl][b][ks][2] = ai2;
  __syncthreads();
  if (t < 64){
    int b2 = t & 31, hl2 = t >> 5;
    int h2 = blockIdx.x*2 + hl2;
    float g0=0.f,g1=0.f,g2=0.f;
    #pragma unroll
    for (int k = 0; k < 8; ++k){
      g0 += part[hl2][b2][k][0]; g1 += part[hl2][b2][k][1]; g2 += part[hl2][b2][k][2];
    }
    float ghr, ghz, ghn;
    if (PRE){
      ghr = ghh[(0*HD + h2)*NB + b2];
      ghz = ghh[(1*HD + h2)*NB + b2];
      ghn = ghh[(2*HD + h2)*NB + b2];
    } else {
      float g3=0.f,g4=0.f,g5=0.f;
      #pragma unroll
      for (int k = 0; k < 8; ++k){
        g3 += part[hl2][b2][k][3]; g4 += part[hl2][b2][k][4]; g5 += part[hl2][b2][k][5];
      }
      ghr = g3; ghz = g4; ghn = g5;
    }
    float gir = g0 + bih[h2], giz = g1 + bih[HD + h2], gin = g2 + bih[2*HD + h2];
    ghr += bhh[h2]; ghz += bhh[HD + h2]; ghn += bhh[2*HD + h2];
    float r = sigf(gir + ghr);
    float z = sigf(giz + ghz);
    float nn = ftanh(gin + r*ghn);
    int idx = (h2 >> 2)*128 + b2*4 + (h2 & 3);
    float hp = ((const float*)h4)[idx];
    outT[idx] = (1.f - z)*nn + z*hp;
  }
}

// ==== fused attention with last-finisher softmax (blocks 0..255)
//      ∥ ghh1 precompute (256..511) ∥ ghh0 precompute (512..767) ====
union __align__(16) AMem {
  struct { __align__(16) float h1s[512]; __align__(16) float wcs[256];
           __align__(16) float Vs[256];  __align__(16) float qs[256];
           __align__(16) float4 qpart[8][64];
           float red[8]; float redc[8]; int redi[8];
           float s_mx, s_den; int s_k; int s_old; } a;
  float part[2][NB][8][6];
};

__global__ __launch_bounds__(512) void k_attn(const float4* __restrict__ h1,
                      const float4* __restrict__ W2T4, const float4* __restrict__ Wf4,
                      const float* __restrict__ bfv, const float* __restrict__ embpos,
                      int m, const float4* __restrict__ encW1,
                      const float4* __restrict__ wc4, const float4* __restrict__ V4,
                      const int* __restrict__ nn, const float* __restrict__ un,
                      float* __restrict__ cov, float* __restrict__ covl,
                      float* __restrict__ sc, float* __restrict__ x4,
                      float* __restrict__ out, const float* __restrict__ encSrc,
                      int alignedA,
                      const float4* __restrict__ h0n4,
                      const float4* __restrict__ Whh0_4, float* __restrict__ ghh0,
                      const float4* __restrict__ Whh1_4, float* __restrict__ ghh1,
                      int* __restrict__ tick){
  __shared__ AMem sm;
  int t = threadIdx.x;
  if (blockIdx.x >= 512){ hh_pre(h0n4, Whh0_4, ghh0, blockIdx.x - 512, t, sm.part); return; }
  if (blockIdx.x >= 256){ hh_pre(h1,   Whh1_4, ghh1, blockIdx.x - 256, t, sm.part); return; }
  int b = blockIdx.x >> 3, seg = blockIdx.x & 7;
  int n = nn[b];
  bool masked = (seg != 0) && (seg*33 > n);
  if (!masked){
    if (t < 128) ((float4*)sm.a.h1s)[t] = h1[t*NB + b];
    else if (t < 192) ((float4*)sm.a.wcs)[t - 128] = wc4[t - 128];
    else if (t < 256) ((float4*)sm.a.Vs)[t - 192] = V4[t - 192];
    __syncthreads();
    // q partials (per block; identical FP order across b's 8 blocks)
    {
      int u4 = t & 63, kq = t >> 6;
      float4 acc = {0.f,0.f,0.f,0.f};
      const float4* w = W2T4 + (long long)(kq*64)*64 + u4;
      const float* hh = sm.a.h1s + kq*64;
      #pragma unroll 4
      for (int k = 0; k < 64; ++k){
        float a = hh[k];
        float4 wv = w[(long long)k*64];
        acc.x += a*wv.x; acc.y += a*wv.y; acc.z += a*wv.z; acc.w += a*wv.w;
      }
      sm.a.qpart[kq][u4] = acc;
    }
    __syncthreads();
    if (t < 64){
      float4 s = sm.a.qpart[0][t];
      #pragma unroll
      for (int k = 1; k < 8; ++k){
        float4 p = sm.a.qpart[k][t];
        s.x += p.x; s.y += p.y; s.z += p.z; s.w += p.w;
      }
      ((float4*)sm.a.qs)[t] = s;
    } else if (seg == 0){
      int w = (t >> 6) - 1;          // 0..6
      int lane = t & 63;
      for (int j = w; j < MS-1; j += 7){
        const float4* wf = Wf4 + (long long)j*128 + lane*2;
        float4 w0 = wf[0], w1v = wf[1];
        const float4* hh4 = (const float4*)sm.a.h1s + lane*2;
        float4 hv0 = hh4[0], hv1 = hh4[1];
        float d = w0.x*hv0.x + w0.y*hv0.y + w0.z*hv0.z + w0.w*hv0.w
                + w1v.x*hv1.x + w1v.y*hv1.y + w1v.z*hv1.z + w1v.w*hv1.w;
        for (int off = 32; off; off >>= 1) d += __shfl_xor(d, off);
        if (lane == 0){
          float th = (m < 1) ? 0.f : sigf(d + bfv[j]);
          out[OFF_ADJ + (long long)b*(MS-1)*MS + (long long)j*MS + m] = th;
          int k = ED + j;
          x4[(k >> 2)*128 + b*4 + (k & 3)] = th;
        }
      }
    }
    if (seg == 0 && t == 0 && m + 1 < MS){
      #pragma unroll
      for (int p = 0; p < PD; ++p){
        int k = ED + MS - 1 + p;
        x4[(k >> 2)*128 + b*4 + (k & 3)] = embpos[(m+1)*PD + p];
      }
    }
    __syncthreads();
    // scores: own 33-row slice only
    {
      int lane = t & 63, wav = t >> 6;
      int s0 = seg*33;
      float4 q4 = ((const float4*)sm.a.qs)[lane];
      float4 wv = ((const float4*)sm.a.wcs)[lane];
      float4 vv = ((const float4*)sm.a.Vs)[lane];
      for (int s = s0 + wav; s < s0 + 33 && s < SD; s += 8){
        if (s > n) continue;
        float cv = cov[b*SD + s];
        float4 e4 = encW1[((long long)b*SD + s)*64 + lane];
        float acc = vv.x*ftanh(e4.x + q4.x + cv*wv.x)
                  + vv.y*ftanh(e4.y + q4.y + cv*wv.y)
                  + vv.z*ftanh(e4.z + q4.z + cv*wv.z)
                  + vv.w*ftanh(e4.w + q4.w + cv*wv.w);
        for (int off = 32; off; off >>= 1) acc += __shfl_xor(acc, off);
        if (lane == 0) sc[b*SD + s] = acc;
      }
    }
    __syncthreads();   // drains all waves' sc stores (vmcnt before barrier)
  }
  // ---- last-finisher ticket: release publishes this block's sc; winner acquires ----
  if (t == 0)
    sm.a.s_old = __hip_atomic_fetch_add(tick + b, 1, __ATOMIC_ACQ_REL,
                                        __HIP_MEMORY_SCOPE_AGENT);
  __syncthreads();
  if (sm.a.s_old != 7) return;
  // ---- winner: full softmax + gumbel argmax + coverage + outputs + gather ----
  int lane = t & 63, wav = t >> 6;
  float sv = (t < SD && t <= n) ? sc[b*SD + t] : -3.4e38f;
  float cv = (t < SD) ? cov[b*SD + t] : 0.f;
  float v1 = sv;
  for (int off = 32; off; off >>= 1) v1 = fmaxf(v1, __shfl_xor(v1, off));
  if (lane == 0) sm.a.red[wav] = v1;
  __syncthreads();
  if (t == 0){
    float mm = sm.a.red[0];
    for (int i = 1; i < 8; ++i) mm = fmaxf(mm, sm.a.red[i]);
    sm.a.s_mx = mm;
  }
  __syncthreads();
  float ev = (t < SD && t <= n) ? __expf(sv - sm.a.s_mx) : 0.f;
  float v2 = ev;
  for (int off = 32; off; off >>= 1) v2 += __shfl_xor(v2, off);
  if (lane == 0) sm.a.red[wav] = v2;
  __syncthreads();
  if (t == 0){
    float ss = 0.f;
    for (int i = 0; i < 8; ++i) ss += sm.a.red[i];
    sm.a.s_den = ss;
  }
  __syncthreads();
  float aj = (t < SD) ? ev / sm.a.s_den : 0.f;
  float yl = -3.4e38f; int idx = SD; float lcl = 0.f;
  if (t < SD){
    float u = un[((long long)m*NB + b)*SD + t];
    float g = -__logf(-__logf(u + 1e-10f) + 1e-10f);
    yl = __logf(aj + 1e-12f) + g;
    idx = t;
    lcl = fminf(aj, cv);
    cov[b*SD + t] = cv + aj;
    out[OFF_ATT + ((long long)b*SD + t)*MS + m] = aj;
  }
  for (int off = 32; off; off >>= 1){
    float oy = __shfl_xor(yl, off); int oi = __shfl_xor(idx, off);
    if (oy > yl || (oy == yl && oi < idx)){ yl = oy; idx = oi; }
  }
  for (int off = 32; off; off >>= 1) lcl += __shfl_xor(lcl, off);
  if (lane == 0){ sm.a.red[wav] = yl; sm.a.redi[wav] = idx; sm.a.redc[wav] = lcl; }
  __syncthreads();
  if (t == 0){
    float by = sm.a.red[0]; int bi = sm.a.redi[0]; float cl = sm.a.redc[0];
    for (int w = 1; w < 8; ++w){
      if (sm.a.red[w] > by || (sm.a.red[w] == by && sm.a.redi[w] < bi)){
        by = sm.a.red[w]; bi = sm.a.redi[w];
      }
      cl += sm.a.redc[w];
    }
    sm.a.s_k = bi;
    covl[b] += cl;
  }
  __syncthreads();
  int kk = sm.a.s_k;
  if (t < SD) out[OFF_PTR + ((long long)b*SD + t)*MS + m] = (t == kk) ? 1.f : 0.f;
  if (t < 128){
    if (alignedA){
      float4 v = ((const float4*)(encSrc + (long long)(b*SD + kk)*ED))[t];
      ((float4*)x4)[t*NB + b] = v;
    } else {
      const float* er = encSrc + (long long)(b*SD + kk)*ED;  // unaligned base
      float4 v; v.x = er[t*4]; v.y = er[t*4+1]; v.z = er[t*4+2]; v.w = er[t*4+3];
      ((float4*)x4)[t*NB + b] = v;
    }
  }
}

__global__ void k_fin(const float* __restrict__ covl, float* __restrict__ out){
  if (threadIdx.x == 0 && blockIdx.x == 0){
    float s = 0.f;
    for (int i = 0; i < NB; ++i) s += covl[i];
    out[OFF_COVL] = s / (float)NB;
  }
}

extern "C" void kernel_launch(void* const* d_in, const int* in_sizes, int n_in,
                              void* d_out, int out_size, void* d_ws, size_t ws_size,
                              hipStream_t stream){
  const float* h_padded    = (const float*)d_in[0];
  const float* hg          = (const float*)d_in[1];
  const int*   num_nodes   = (const int*)  d_in[2];
  const float* u_noise     = (const float*)d_in[3];
  const float* emb_special = (const float*)d_in[4];
  const float* emb_pos     = (const float*)d_in[5];
  const float* Wp          = (const float*)d_in[6];
  const float* bp          = (const float*)d_in[7];
  const float* W_ih0       = (const float*)d_in[8];
  const float* W_hh0       = (const float*)d_in[9];
  const float* b_ih0       = (const float*)d_in[10];
  const float* b_hh0       = (const float*)d_in[11];
  const float* W_ih1       = (const float*)d_in[12];
  const float* W_hh1       = (const float*)d_in[13];
  const float* b_ih1       = (const float*)d_in[14];
  const float* b_hh1       = (const float*)d_in[15];
  const float* W1          = (const float*)d_in[16];
  const float* W2          = (const float*)d_in[17];
  const float* wc          = (const float*)d_in[18];
  const float* V           = (const float*)d_in[19];
  const float* Wf          = (const float*)d_in[20];
  const float* bf          = (const float*)d_in[21];
  float* out = (float*)d_out;

  float* ws      = (float*)d_ws;
  float* encW1   = ws;  ws += (long long)NB*SD*UD;   // 2,105,344
  float* Wih0_4  = ws;  ws += (long long)1536*XP;    // 884,736
  float* W2T     = ws;  ws += (long long)UD*ED;      // 131,072
  float* x4      = ws;  ws += XP*NB;                 // 18,432
  float* h0      = ws;  ws += 2*HD*NB;               // 32,768
  float* h1      = ws;  ws += 2*HD*NB;               // 32,768
  float* cov     = ws;  ws += NB*SD;                 // 8,224
  float* covl    = ws;  ws += NB;                    // 32
  float* sc      = ws;  ws += NB*SD;                 // 8,224
  float* ghh0    = ws;  ws += 3*HD*NB;               // 49,152
  float* ghh1    = ws;  ws += 3*HD*NB;               // 49,152
  int*   tick    = (int*)ws; ws += MS*NB;            // 1,024 (per-step ticket slots)
  float* encA    = ws;  // optional aligned enc copy: +4,210,688 floats
  size_t used_base = (size_t)((char*)ws - (char*)d_ws);
  int useA = (ws_size >= used_base + (size_t)NB*SD*ED*sizeof(float)) ? 1 : 0;
  const float* encSrc = useA ? encA : (out + OFF_ENC);

  k_pro<<<4756, 256, 0, stream>>>(h_padded, hg, emb_special, emb_pos, W1, W_ih0, W2,
                                  num_nodes, (const float4*)Wp, bp, out, encA, useA,
                                  (float4*)encW1, x4, cov, covl, Wih0_4, W2T, h0, h1,
                                  tick);

  for (int m = 0; m < MS; ++m){
    float* h0c = h0 + (m & 1)*HD*NB;
    float* h0n = h0 + ((m + 1) & 1)*HD*NB;
    float* h1c = h1 + (m & 1)*HD*NB;
    float* h1n = h1 + ((m + 1) & 1)*HD*NB;
    if (m == 0){
      k_gru<18,false><<<256, 512, 0, stream>>>((const float4*)x4, (const float4*)h0c,
          (const float4*)Wih0_4, (const float4*)W_hh0, b_ih0, b_hh0, h0n, nullptr);
      k_gru<16,false><<<256, 512, 0, stream>>>((const float4*)h0n, (const float4*)h1c,
          (const float4*)W_ih1, (const float4*)W_hh1, b_ih1, b_hh1, h1n, nullptr);
    } else {
      k_gru<18,true><<<256, 512, 0, stream>>>((const float4*)x4, (const float4*)h0c,
          (const float4*)Wih0_4, (const float4*)W_hh0, b_ih0, b_hh0, h0n, ghh0);
      k_gru<16,true><<<256, 512, 0, stream>>>((const float4*)h0n, (const float4*)h1c,
          (const float4*)W_ih1, (const float4*)W_hh1, b_ih1, b_hh1, h1n, ghh1);
    }
    k_attn<<<768, 512, 0, stream>>>((const float4*)h1n, (const float4*)W2T,
        (const float4*)Wf, bf, emb_pos, m, (const float4*)encW1,
        (const float4*)wc, (const float4*)V, num_nodes, u_noise,
        cov, covl, sc, x4, out, encSrc, useA,
        (const float4*)h0n, (const float4*)W_hh0, ghh0,
        (const float4*)W_hh1, ghh1, tick + m*NB);
  }
  k_fin<<<1, 64, 0, stream>>>(covl, out);
}

// Round 15
// 1205.911 us; speedup vs baseline: 1.4666x; 1.1312x over previous
//
#include <hip/hip_runtime.h>

constexpr int NB  = 32;     // batch
constexpr int NMX = 256;    // NMAX
constexpr int ED  = 512;    // E
constexpr int HD  = 512;    // H
constexpr int UD  = 256;    // U
constexpr int MS  = 32;     // M steps
constexpr int PD  = 4;      // P
constexpr int SD  = 257;    // S = NMAX+1
constexpr int IL0 = 547;    // E + (M-1) + P
constexpr int XP  = 576;    // padded layer-0 input (18 f4 x 8 ks)

constexpr long long OFF_PTR  = 0;
constexpr long long OFF_COVL = (long long)NB*SD*MS;              // 263168
constexpr long long OFF_ENC  = OFF_COVL + 1;                     // 263169 (NOT 16B-aligned)
constexpr long long OFF_ADJ  = OFF_ENC + (long long)NB*SD*ED;    // 4473857
constexpr long long OFF_ATT  = OFF_ADJ + (long long)NB*(MS-1)*MS;// 4505601

__device__ __forceinline__ float sigf(float x){ return 1.0f/(1.0f + __expf(-x)); }
__device__ __forceinline__ float ftanh(float x){ float e = __expf(2.0f*x); return 1.0f - 2.0f/(e + 1.0f); }

// ==== merged prologue: encW1 GEMM + hid0 + enc-write + misc (round-12 proven) ====
__global__ __launch_bounds__(256) void k_pro(const float* __restrict__ hp,
    const float* __restrict__ hg, const float* __restrict__ embsp,
    const float* __restrict__ embpos, const float* __restrict__ W1,
    const float* __restrict__ Wih0, const float* __restrict__ W2,
    const int* __restrict__ nn, const float4* __restrict__ Wp4,
    const float* __restrict__ bp,
    float* __restrict__ out, float* __restrict__ encA, int useA,
    float4* __restrict__ encW1,
    float* __restrict__ x4, float* __restrict__ cov, float* __restrict__ covl,
    float* __restrict__ Wih0_4, float* __restrict__ W2T,
    float* __restrict__ h0, float* __restrict__ h1){
  __shared__ __align__(16) float As[16][68];
  __shared__ __align__(16) float Bs[16][68];
  int blk = blockIdx.x, t = threadIdx.x;
  if (blk < 516){
    int bm = blk >> 2, bn = blk & 3;
    int m0 = bm*64, n0 = bn*64;
    int tm = t >> 4, tn = t & 15;
    float4 acc[4];
    #pragma unroll
    for (int i = 0; i < 4; ++i) acc[i] = {0.f,0.f,0.f,0.f};
    int arow = t >> 2, akq = t & 3;
    int r = m0 + arow;
    int amode = 0;
    const float* abase = embsp + ED;
    if (r < NB*SD){
      int ab = r / SD, as = r - ab*SD;
      if (as == 0) amode = 1;
      else if (as <= nn[ab]){ amode = 2; abase = hp + ((long long)ab*NMX + (as-1))*ED; }
    }
    int bk = t & 15, bu = t >> 4;
    for (int k0 = 0; k0 < 512; k0 += 16){
      float4 av = {0.f,0.f,0.f,0.f};
      if (amode) av = *(const float4*)(abase + k0 + akq*4);
      float bv[4];
      #pragma unroll
      for (int j = 0; j < 4; ++j)
        bv[j] = W1[(long long)(n0 + bu*4 + j)*ED + k0 + bk];
      __syncthreads();
      As[akq*4 + 0][arow] = av.x;
      As[akq*4 + 1][arow] = av.y;
      As[akq*4 + 2][arow] = av.z;
      As[akq*4 + 3][arow] = av.w;
      *(float4*)&Bs[bk][bu*4] = make_float4(bv[0], bv[1], bv[2], bv[3]);
      __syncthreads();
      #pragma unroll
      for (int kk = 0; kk < 16; ++kk){
        float4 a = *(const float4*)&As[kk][tm*4];
        float4 bq = *(const float4*)&Bs[kk][tn*4];
        acc[0].x += a.x*bq.x; acc[0].y += a.x*bq.y; acc[0].z += a.x*bq.z; acc[0].w += a.x*bq.w;
        acc[1].x += a.y*bq.x; acc[1].y += a.y*bq.y; acc[1].z += a.y*bq.z; acc[1].w += a.y*bq.w;
        acc[2].x += a.z*bq.x; acc[2].y += a.z*bq.y; acc[2].z += a.z*bq.z; acc[2].w += a.z*bq.w;
        acc[3].x += a.w*bq.x; acc[3].y += a.w*bq.y; acc[3].z += a.w*bq.z; acc[3].w += a.w*bq.w;
      }
    }
    #pragma unroll
    for (int i = 0; i < 4; ++i){
      int rr = m0 + tm*4 + i;
      if (rr < NB*SD) encW1[(long long)rr*64 + (n0 >> 2) + tn] = acc[i];
    }
  } else if (blk < 644){
    int b = t & 31;
    int row = (blk - 516)*8 + (t >> 5);            // 0..1023
    const float4* w = Wp4 + (long long)row*128;
    const float4* xg = (const float4*)(hg + (long long)b*ED);
    float acc = bp[row];
    #pragma unroll 4
    for (int i = 0; i < 128; ++i){
      float4 wv = w[i], xv = xg[i];
      acc += wv.x*xv.x + wv.y*xv.y + wv.z*xv.z + wv.w*xv.w;
    }
    float v = ftanh(acc);
    int h = row & 511;
    int idx = (h >> 2)*128 + b*4 + (h & 3);
    if (row < HD) h0[idx] = v;
    else          h1[idx] = v;
  } else {
    int eb = blk - 644;                             // 0..4111
    {
      int r = eb*2 + (t >> 7);
      int tid = t & 127;
      int b = r / SD, s = r - b*SD;
      float4 v = {0.f,0.f,0.f,0.f};
      if (s == 0) v = *(const float4*)(embsp + ED + tid*4);
      else if (s <= nn[b]) v = *(const float4*)(hp + ((long long)b*NMX + (s-1))*ED + tid*4);
      float* dst = out + OFF_ENC + (long long)r*ED + tid*4;
      dst[0] = v.x; dst[1] = v.y; dst[2] = v.z; dst[3] = v.w;
      if (useA) *(float4*)(encA + (long long)r*ED + tid*4) = v;
    }
    const int N0 = XP*NB;              // 18432 x4
    const int N1 = N0 + NB*SD;         // +8224 cov
    const int N2 = N1 + NB;            // +32 covl
    const int N3 = N2 + 1536*XP;       // Wih0 repack
    const int N4 = N3 + ED*UD;         // W2T
    for (int i = eb*256 + t; i < N4; i += 4112*256){
      if (i < N0){
        int kb = i >> 7, rr = i & 3;
        int k = kb*4 + rr;
        float v;
        if (k < ED) v = embsp[k];
        else if (k < ED + MS - 1) v = 0.f;
        else if (k < IL0) v = embpos[k - (ED + MS - 1)];
        else v = 0.f;
        x4[i] = v;
      } else if (i < N1){
        cov[i - N0] = 0.f;
      } else if (i < N2){
        covl[i - N1] = 0.f;
      } else if (i < N3){
        int j = i - N2; int row = j / XP, c = j % XP;
        Wih0_4[j] = (c < IL0) ? Wih0[(long long)row*IL0 + c] : 0.f;
      } else {
        int j = i - N3; int k = j / UD, u = j % UD;
        W2T[j] = W2[(long long)u*HD + k];
      }
    }
  }
}

// ==== hh-precompute: ghh[g][h][b] = h_prev @ Whh[g*H+h] (round-12 proven) ====
__device__ __forceinline__ void hh_pre(const float4* __restrict__ h4,
    const float4* __restrict__ Whh4, float* __restrict__ ghh,
    int bh, int t, float (*part)[NB][8][6]){
  int b = t & 31, ks = (t >> 5) & 7, hl = (t >> 8) & 1;
  int h = bh*2 + hl;
  float a0 = 0.f, a1 = 0.f, a2 = 0.f;
  const float4* w0 = Whh4 + (long long)(0*HD + h)*128 + ks*16;
  const float4* w1 = Whh4 + (long long)(1*HD + h)*128 + ks*16;
  const float4* w2 = Whh4 + (long long)(2*HD + h)*128 + ks*16;
  const float4* hb = h4 + (long long)(ks*16)*NB + b;
  #pragma unroll
  for (int kb = 0; kb < 16; ++kb){
    float4 xv = hb[kb*NB];
    float4 a = w0[kb], c = w1[kb], d = w2[kb];
    a0 += xv.x*a.x + xv.y*a.y + xv.z*a.z + xv.w*a.w;
    a1 += xv.x*c.x + xv.y*c.y + xv.z*c.z + xv.w*c.w;
    a2 += xv.x*d.x + xv.y*d.y + xv.z*d.z + xv.w*d.w;
  }
  part[hl][b][ks][0] = a0; part[hl][b][ks][1] = a1; part[hl][b][ks][2] = a2;
  __syncthreads();
  if (t < 64){
    int b2 = t & 31, hl2 = t >> 5;
    int h2 = bh*2 + hl2;
    float g0 = 0.f, g1 = 0.f, g2 = 0.f;
    #pragma unroll
    for (int k = 0; k < 8; ++k){
      g0 += part[hl2][b2][k][0]; g1 += part[hl2][b2][k][1]; g2 += part[hl2][b2][k][2];
    }
    ghh[(0*HD + h2)*NB + b2] = g0;
    ghh[(1*HD + h2)*NB + b2] = g1;
    ghh[(2*HD + h2)*NB + b2] = g2;
  }
}

// ==== GRU layer step; PRE -> hh gate sums read from ghh (round-12 proven) ====
template<int PER, bool PRE>
__global__ __launch_bounds__(512) void k_gru(const float4* __restrict__ x4,
                      const float4* __restrict__ h4,
                      const float4* __restrict__ Wih4, const float4* __restrict__ Whh4,
                      const float* __restrict__ bih, const float* __restrict__ bhh,
                      float* __restrict__ outT, const float* __restrict__ ghh){
  constexpr int NI4 = PER*8;
  __shared__ float part[2][NB][8][6];
  int t = threadIdx.x;
  int b = t & 31, ks = (t >> 5) & 7, hl = (t >> 8) & 1;
  int h = blockIdx.x*2 + hl;
  float ai0 = 0.f, ai1 = 0.f, ai2 = 0.f;
  {
    const float4* w0 = Wih4 + (long long)(0*HD + h)*NI4 + ks*PER;
    const float4* w1 = Wih4 + (long long)(1*HD + h)*NI4 + ks*PER;
    const float4* w2 = Wih4 + (long long)(2*HD + h)*NI4 + ks*PER;
    const float4* xb = x4 + (long long)(ks*PER)*NB + b;
    #pragma unroll
    for (int kb = 0; kb < PER; ++kb){
      float4 xv = xb[kb*NB];
      float4 a = w0[kb], c = w1[kb], d = w2[kb];
      ai0 += xv.x*a.x + xv.y*a.y + xv.z*a.z + xv.w*a.w;
      ai1 += xv.x*c.x + xv.y*c.y + xv.z*c.z + xv.w*c.w;
      ai2 += xv.x*d.x + xv.y*d.y + xv.z*d.z + xv.w*d.w;
    }
  }
  if (!PRE){
    float ah0 = 0.f, ah1 = 0.f, ah2 = 0.f;
    const float4* w0 = Whh4 + (long long)(0*HD + h)*128 + ks*16;
    const float4* w1 = Whh4 + (long long)(1*HD + h)*128 + ks*16;
    const float4* w2 = Whh4 + (long long)(2*HD + h)*128 + ks*16;
    const float4* hb = h4 + (long long)(ks*16)*NB + b;
    #pragma unroll
    for (int kb = 0; kb < 16; ++kb){
      float4 xv = hb[kb*NB];
      float4 a = w0[kb], c = w1[kb], d = w2[kb];
      ah0 += xv.x*a.x + xv.y*a.y + xv.z*a.z + xv.w*a.w;
      ah1 += xv.x*c.x + xv.y*c.y + xv.z*c.z + xv.w*c.w;
      ah2 += xv.x*d.x + xv.y*d.y + xv.z*d.z + xv.w*d.w;
    }
    part[hl][b][ks][3] = ah0; part[hl][b][ks][4] = ah1; part[hl][b][ks][5] = ah2;
  }
  part[hl][b][ks][0] = ai0; part[hl][b][ks][1] = ai1; part[hl][b][ks][2] = ai2;
  __syncthreads();
  if (t < 64){
    int b2 = t & 31, hl2 = t >> 5;
    int h2 = blockIdx.x*2 + hl2;
    float g0=0.f,g1=0.f,g2=0.f;
    #pragma unroll
    for (int k = 0; k < 8; ++k){
      g0 += part[hl2][b2][k][0]; g1 += part[hl2][b2][k][1]; g2 += part[hl2][b2][k][2];
    }
    float ghr, ghz, ghn;
    if (PRE){
      ghr = ghh[(0*HD + h2)*NB + b2];
      ghz = ghh[(1*HD + h2)*NB + b2];
      ghn = ghh[(2*HD + h2)*NB + b2];
    } else {
      float g3=0.f,g4=0.f,g5=0.f;
      #pragma unroll
      for (int k = 0; k < 8; ++k){
        g3 += part[hl2][b2][k][3]; g4 += part[hl2][b2][k][4]; g5 += part[hl2][b2][k][5];
      }
      ghr = g3; ghz = g4; ghn = g5;
    }
    float gir = g0 + bih[h2], giz = g1 + bih[HD + h2], gin = g2 + bih[2*HD + h2];
    ghr += bhh[h2]; ghz += bhh[HD + h2]; ghn += bhh[2*HD + h2];
    float r = sigf(gir + ghr);
    float z = sigf(giz + ghz);
    float nn = ftanh(gin + r*ghn);
    int idx = (h2 >> 2)*128 + b2*4 + (h2 & 3);
    float hp = ((const float*)h4)[idx];
    outT[idx] = (1.f - z)*nn + z*hp;
  }
}

// ==== q + theta + scores (blocks 0..255) ∥ gru1-hh precompute (blocks 256..511) ====
__global__ __launch_bounds__(512) void k_qs(const float4* __restrict__ h1,
                      const float4* __restrict__ W2T4, const float4* __restrict__ Wf4,
                      const float* __restrict__ bfv, const float* __restrict__ embpos,
                      int m, const float4* __restrict__ encW1,
                      const float4* __restrict__ wc4, const float4* __restrict__ V4,
                      const int* __restrict__ nn,
                      const float* __restrict__ cov, float* __restrict__ sc,
                      float* __restrict__ x4, float* __restrict__ out,
                      const float4* __restrict__ Whh1_4, float* __restrict__ ghh1){
  union QMem {
    struct { float h1s[512]; float wcs[256]; float Vs[256]; float qs[256];
             float4 qpart[8][64]; } q;
    float part[2][NB][8][6];
  };
  __shared__ __align__(16) QMem sm;
  int t = threadIdx.x;
  if (blockIdx.x >= 256){
    hh_pre(h1, Whh1_4, ghh1, blockIdx.x - 256, t, sm.part);
    return;
  }
  int b = blockIdx.x >> 3, seg = blockIdx.x & 7;
  int n = nn[b];
  if (seg != 0 && seg*33 > n) return;
  if (t < 128) ((float4*)sm.q.h1s)[t] = h1[t*NB + b];
  else if (t < 192) ((float4*)sm.q.wcs)[t - 128] = wc4[t - 128];
  else if (t < 256) ((float4*)sm.q.Vs)[t - 192] = V4[t - 192];
  __syncthreads();
  {
    int u4 = t & 63, kq = t >> 6;
    float4 acc = {0.f,0.f,0.f,0.f};
    const float4* w = W2T4 + (long long)(kq*64)*64 + u4;
    const float* hh = sm.q.h1s + kq*64;
    #pragma unroll 4
    for (int k = 0; k < 64; ++k){
      float a = hh[k];
      float4 wv = w[(long long)k*64];
      acc.x += a*wv.x; acc.y += a*wv.y; acc.z += a*wv.z; acc.w += a*wv.w;
    }
    sm.q.qpart[kq][u4] = acc;
  }
  __syncthreads();
  if (t < 64){
    float4 s = sm.q.qpart[0][t];
    #pragma unroll
    for (int k = 1; k < 8; ++k){
      float4 p = sm.q.qpart[k][t];
      s.x += p.x; s.y += p.y; s.z += p.z; s.w += p.w;
    }
    ((float4*)sm.q.qs)[t] = s;
  } else if (seg == 0){
    int w = (t >> 6) - 1;          // 0..6
    int lane = t & 63;
    for (int j = w; j < MS-1; j += 7){
      const float4* wf = Wf4 + (long long)j*128 + lane*2;
      float4 w0 = wf[0], w1v = wf[1];
      const float4* hh4 = (const float4*)sm.q.h1s + lane*2;
      float4 hv0 = hh4[0], hv1 = hh4[1];
      float d = w0.x*hv0.x + w0.y*hv0.y + w0.z*hv0.z + w0.w*hv0.w
              + w1v.x*hv1.x + w1v.y*hv1.y + w1v.z*hv1.z + w1v.w*hv1.w;
      for (int off = 32; off; off >>= 1) d += __shfl_xor(d, off);
      if (lane == 0){
        float th = (m < 1) ? 0.f : sigf(d + bfv[j]);
        out[OFF_ADJ + (long long)b*(MS-1)*MS + (long long)j*MS + m] = th;
        int k = ED + j;
        x4[(k >> 2)*128 + b*4 + (k & 3)] = th;
      }
    }
  }
  if (seg == 0 && t == 0 && m + 1 < MS){
    #pragma unroll
    for (int p = 0; p < PD; ++p){
      int k = ED + MS - 1 + p;
      x4[(k >> 2)*128 + b*4 + (k & 3)] = embpos[(m+1)*PD + p];
    }
  }
  __syncthreads();
  int lane = t & 63, wav = t >> 6;
  int s0 = seg*33;
  float4 q4 = ((const float4*)sm.q.qs)[lane];
  float4 wv = ((const float4*)sm.q.wcs)[lane];
  float4 vv = ((const float4*)sm.q.Vs)[lane];
  for (int s = s0 + wav; s < s0 + 33 && s < SD; s += 8){
    if (s > n) continue;                    // masked rows never consumed
    float cv = cov[b*SD + s];
    float4 e4 = encW1[((long long)b*SD + s)*64 + lane];
    float acc = vv.x*ftanh(e4.x + q4.x + cv*wv.x)
              + vv.y*ftanh(e4.y + q4.y + cv*wv.y)
              + vv.z*ftanh(e4.z + q4.z + cv*wv.z)
              + vv.w*ftanh(e4.w + q4.w + cv*wv.w);
    for (int off = 32; off; off >>= 1) acc += __shfl_xor(acc, off);
    if (lane == 0) sc[b*SD + s] = acc;
  }
}

// ==== softmax/gumbel/cov/staged-outputs/gather (0..31) ∥ gru0-hh precompute ====
__global__ __launch_bounds__(512) void k_soft(const float* __restrict__ sc,
                      const int* __restrict__ nn, const float* __restrict__ un, int m,
                      float* __restrict__ cov, float* __restrict__ covl,
                      float* __restrict__ att_st, float* __restrict__ ptr_st,
                      float4* __restrict__ x4,
                      const float* __restrict__ encSrc, int alignedA,
                      const float4* __restrict__ h0n4,
                      const float4* __restrict__ Whh0_4, float* __restrict__ ghh0){
  union SMem {
    struct { float red[8]; float redc[8]; int redi[8]; float s_mx, s_den; int s_k; } s;
    float part[2][NB][8][6];
  };
  __shared__ __align__(16) SMem sm;
  int t = threadIdx.x;
  if (blockIdx.x >= 32){
    hh_pre(h0n4, Whh0_4, ghh0, blockIdx.x - 32, t, sm.part);
    return;
  }
  int b = blockIdx.x;
  int lane = t & 63, wav = t >> 6;
  int n = nn[b];
  float sv = (t < SD) ? sc[b*SD + t] : -3.4e38f;
  float cv = (t < SD) ? cov[b*SD + t] : 0.f;
  float v1 = (t < SD && t <= n) ? sv : -3.4e38f;
  for (int off = 32; off; off >>= 1) v1 = fmaxf(v1, __shfl_xor(v1, off));
  if (lane == 0) sm.s.red[wav] = v1;
  __syncthreads();
  if (t == 0){
    float mm = sm.s.red[0];
    for (int i = 1; i < 8; ++i) mm = fmaxf(mm, sm.s.red[i]);
    sm.s.s_mx = mm;
  }
  __syncthreads();
  float ev = (t < SD && t <= n) ? __expf(sv - sm.s.s_mx) : 0.f;
  float v2 = ev;
  for (int off = 32; off; off >>= 1) v2 += __shfl_xor(v2, off);
  if (lane == 0) sm.s.red[wav] = v2;
  __syncthreads();
  if (t == 0){
    float ss = 0.f;
    for (int i = 0; i < 8; ++i) ss += sm.s.red[i];
    sm.s.s_den = ss;
  }
  __syncthreads();
  float aj = (t < SD) ? ev / sm.s.s_den : 0.f;
  float yl = -3.4e38f; int idx = SD; float lcl = 0.f;
  if (t < SD){
    float u = un[((long long)m*NB + b)*SD + t];
    float g = -__logf(-__logf(u + 1e-10f) + 1e-10f);
    yl = __logf(aj + 1e-12f) + g;
    idx = t;
    lcl = fminf(aj, cv);
    cov[b*SD + t] = cv + aj;
    att_st[((long long)m*NB + b)*SD + t] = aj;       // coalesced staging
  }
  for (int off = 32; off; off >>= 1){
    float oy = __shfl_xor(yl, off); int oi = __shfl_xor(idx, off);
    if (oy > yl || (oy == yl && oi < idx)){ yl = oy; idx = oi; }
  }
  for (int off = 32; off; off >>= 1) lcl += __shfl_xor(lcl, off);
  if (lane == 0){ sm.s.red[wav] = yl; sm.s.redi[wav] = idx; sm.s.redc[wav] = lcl; }
  __syncthreads();
  if (t == 0){
    float by = sm.s.red[0]; int bi = sm.s.redi[0]; float cl = sm.s.redc[0];
    for (int w = 1; w < 8; ++w){
      if (sm.s.red[w] > by || (sm.s.red[w] == by && sm.s.redi[w] < bi)){
        by = sm.s.red[w]; bi = sm.s.redi[w];
      }
      cl += sm.s.redc[w];
    }
    sm.s.s_k = bi;
    covl[b] += cl;
  }
  __syncthreads();
  int kk = sm.s.s_k;
  if (t < SD) ptr_st[((long long)m*NB + b)*SD + t] = (t == kk) ? 1.f : 0.f;
  if (t < 128){
    if (alignedA){
      float4 v = ((const float4*)(encSrc + (long long)(b*SD + kk)*ED))[t];
      x4[t*NB + b] = v;
    } else {
      const float* er = encSrc + (long long)(b*SD + kk)*ED;  // unaligned base
      float4 v; v.x = er[t*4]; v.y = er[t*4+1]; v.z = er[t*4+2]; v.w = er[t*4+3];
      x4[t*NB + b] = v;
    }
  }
}

// ==== epilogue: transpose staged [m][b][s] -> out [b][s][m] (+ cov_loss) ====
__global__ __launch_bounds__(256) void k_tr(const float* __restrict__ att_st,
                      const float* __restrict__ ptr_st,
                      const float* __restrict__ covl, float* __restrict__ out){
  __shared__ float tile[32][33];
  int blk = blockIdx.x, t = threadIdx.x;
  if (blk == 576){
    if (t == 0){
      float s = 0.f;
      for (int i = 0; i < NB; ++i) s += covl[i];
      out[OFF_COVL] = s / (float)NB;
    }
    return;
  }
  int kind = blk / 288, idx = blk % 288;
  int b = idx / 9, ch = idx % 9;
  int s0 = ch*32;
  const float* st = kind ? ptr_st : att_st;
  long long obase = kind ? OFF_PTR : OFF_ATT;
  #pragma unroll
  for (int p = 0; p < 4; ++p){
    int mm = p*8 + (t >> 5), si = t & 31;
    int s = s0 + si;
    if (s < SD) tile[si][mm] = st[((long long)mm*NB + b)*SD + s];
  }
  __syncthreads();
  #pragma unroll
  for (int p = 0; p < 4; ++p){
    int sr = p*8 + (t >> 5), mm = t & 31;
    int s = s0 + sr;
    if (s < SD) out[obase + ((long long)b*SD + s)*MS + mm] = tile[sr][mm];
  }
}

extern "C" void kernel_launch(void* const* d_in, const int* in_sizes, int n_in,
                              void* d_out, int out_size, void* d_ws, size_t ws_size,
                              hipStream_t stream){
  const float* h_padded    = (const float*)d_in[0];
  const float* hg          = (const float*)d_in[1];
  const int*   num_nodes   = (const int*)  d_in[2];
  const float* u_noise     = (const float*)d_in[3];
  const float* emb_special = (const float*)d_in[4];
  const float* emb_pos     = (const float*)d_in[5];
  const float* Wp          = (const float*)d_in[6];
  const float* bp          = (const float*)d_in[7];
  const float* W_ih0       = (const float*)d_in[8];
  const float* W_hh0       = (const float*)d_in[9];
  const float* b_ih0       = (const float*)d_in[10];
  const float* b_hh0       = (const float*)d_in[11];
  const float* W_ih1       = (const float*)d_in[12];
  const float* W_hh1       = (const float*)d_in[13];
  const float* b_ih1       = (const float*)d_in[14];
  const float* b_hh1       = (const float*)d_in[15];
  const float* W1          = (const float*)d_in[16];
  const float* W2          = (const float*)d_in[17];
  const float* wc          = (const float*)d_in[18];
  const float* V           = (const float*)d_in[19];
  const float* Wf          = (const float*)d_in[20];
  const float* bf          = (const float*)d_in[21];
  float* out = (float*)d_out;

  float* ws      = (float*)d_ws;
  float* encW1   = ws;  ws += (long long)NB*SD*UD;   // 2,105,344
  float* Wih0_4  = ws;  ws += (long long)1536*XP;    // 884,736
  float* W2T     = ws;  ws += (long long)UD*ED;      // 131,072
  float* x4      = ws;  ws += XP*NB;                 // 18,432
  float* h0      = ws;  ws += 2*HD*NB;               // 32,768
  float* h1      = ws;  ws += 2*HD*NB;               // 32,768
  float* cov     = ws;  ws += NB*SD;                 // 8,224
  float* covl    = ws;  ws += NB;                    // 32
  float* sc      = ws;  ws += NB*SD;                 // 8,224
  float* ghh0    = ws;  ws += 3*HD*NB;               // 49,152
  float* ghh1    = ws;  ws += 3*HD*NB;               // 49,152
  float* att_st  = ws;  ws += (long long)MS*NB*SD;   // 263,168
  float* ptr_st  = ws;  ws += (long long)MS*NB*SD;   // 263,168
  float* encA    = ws;  // optional aligned enc copy: +4,210,688 floats
  size_t used_base = (size_t)((char*)ws - (char*)d_ws);
  int useA = (ws_size >= used_base + (size_t)NB*SD*ED*sizeof(float)) ? 1 : 0;
  const float* encSrc = useA ? encA : (out + OFF_ENC);

  k_pro<<<4756, 256, 0, stream>>>(h_padded, hg, emb_special, emb_pos, W1, W_ih0, W2,
                                  num_nodes, (const float4*)Wp, bp, out, encA, useA,
                                  (float4*)encW1, x4, cov, covl, Wih0_4, W2T, h0, h1);

  for (int m = 0; m < MS; ++m){
    float* h0c = h0 + (m & 1)*HD*NB;
    float* h0n = h0 + ((m + 1) & 1)*HD*NB;
    float* h1c = h1 + (m & 1)*HD*NB;
    float* h1n = h1 + ((m + 1) & 1)*HD*NB;
    if (m == 0){
      k_gru<18,false><<<256, 512, 0, stream>>>((const float4*)x4, (const float4*)h0c,
          (const float4*)Wih0_4, (const float4*)W_hh0, b_ih0, b_hh0, h0n, nullptr);
      k_gru<16,false><<<256, 512, 0, stream>>>((const float4*)h0n, (const float4*)h1c,
          (const float4*)W_ih1, (const float4*)W_hh1, b_ih1, b_hh1, h1n, nullptr);
    } else {
      k_gru<18,true><<<256, 512, 0, stream>>>((const float4*)x4, (const float4*)h0c,
          (const float4*)Wih0_4, (const float4*)W_hh0, b_ih0, b_hh0, h0n, ghh0);
      k_gru<16,true><<<256, 512, 0, stream>>>((const float4*)h0n, (const float4*)h1c,
          (const float4*)W_ih1, (const float4*)W_hh1, b_ih1, b_hh1, h1n, ghh1);
    }
    k_qs  <<<512, 512, 0, stream>>>((const float4*)h1n, (const float4*)W2T,
        (const float4*)Wf, bf, emb_pos, m, (const float4*)encW1,
        (const float4*)wc, (const float4*)V, num_nodes, cov, sc, x4, out,
        (const float4*)W_hh1, ghh1);
    k_soft<<<288, 512, 0, stream>>>(sc, num_nodes, u_noise, m, cov, covl,
        att_st, ptr_st, (float4*)x4, encSrc, useA,
        (const float4*)h0n, (const float4*)W_hh0, ghh0);
  }
  k_tr<<<577, 256, 0, stream>>>(att_st, ptr_st, covl, out);
}